// Round 9
// baseline (384.811 us; speedup 1.0000x reference)
//
#include <hip/hip_runtime.h>
#include <hip/hip_bf16.h>

#define NN 100000
#define DD 128
#define HH 256

#define NBKT 391   // ceil(NN/256) buckets of 256 nodes (bucket = dst>>8)
#define ABLK 256   // partition blocks for phases A/B (1 per CU)

typedef _Float16 half_t;
typedef _Float16 half8 __attribute__((ext_vector_type(8)));
typedef _Float16 half4_t __attribute__((ext_vector_type(4)));
typedef float floatx4 __attribute__((ext_vector_type(4)));

// ---------------- CSR build, LDS-atomic counting sort ----------------

// Phase A: per-block bucket histogram; cnt[b*ABLK+blk], tot[b] (tot pre-zeroed).
// Blocks >= ABLK do the weight transposes instead (fused launch).
__global__ __launch_bounds__(256) void hist_bkt(const int* __restrict__ dst,
                                                int* __restrict__ cnt,
                                                int* __restrict__ tot,
                                                const float* __restrict__ W1,
                                                const float* __restrict__ W2,
                                                half_t* __restrict__ W1t,
                                                half_t* __restrict__ W2t,
                                                int E, int epb) {
    __shared__ int h[NBKT];
    if (blockIdx.x >= ABLK) {
        // transpose both weights: 8 blocks, grid-stride over 2*DD*HH elements
        for (int i = (blockIdx.x - ABLK) * 256 + (int)threadIdx.x;
             i < 2 * DD * HH; i += 8 * 256) {
            if (i < DD * HH) {                   // W1: K=DD, C=HH
                int k = i / HH, c = i - k * HH;
                W1t[(size_t)c * DD + k] = (half_t)W1[i];
            } else {                             // W2: K=HH, C=DD
                int j = i - DD * HH;
                int k = j / DD, c = j - k * DD;
                W2t[(size_t)c * HH + k] = (half_t)W2[j];
            }
        }
        return;
    }
    for (int i = threadIdx.x; i < NBKT; i += 256) h[i] = 0;
    __syncthreads();
    int base = blockIdx.x * epb;
    int end = min(base + epb, E);
    for (int e = base + (int)threadIdx.x; e < end; e += 256)
        atomicAdd(&h[dst[e] >> 8], 1);
    __syncthreads();
    for (int i = threadIdx.x; i < NBKT; i += 256) {
        int v = h[i];
        cnt[i * ABLK + blockIdx.x] = v;
        if (v) atomicAdd(&tot[i], v);
    }
}

// Fused scan: each block b recomputes the bucket prefix (391 ints, trivial) and
// scans its own cnt[b][0..ABLK-1] -> bktStart[b] + blockOff[b][*].
__global__ __launch_bounds__(512) void scan_all(const int* __restrict__ tot,
                                                const int* __restrict__ cnt,
                                                int* __restrict__ bktStart,
                                                int* __restrict__ blockOff) {
    __shared__ int s[512];
    int b = blockIdx.x, t = threadIdx.x;
    int v = (t < NBKT) ? tot[t] : 0;
    s[t] = v;
    __syncthreads();
    for (int off = 1; off < 512; off <<= 1) {
        int u = (t >= off) ? s[t - off] : 0;
        __syncthreads();
        s[t] += u;
        __syncthreads();
    }
    int bs = (b > 0) ? s[b - 1] : 0;       // exclusive start of bucket b
    int tail = s[NBKT - 1];                // == E
    __syncthreads();
    if (t == 0) {
        bktStart[b] = bs;
        if (b == NBKT - 1) bktStart[NBKT] = tail;
    }
    int c = (t < ABLK) ? cnt[b * ABLK + t] : 0;
    s[t] = c;
    __syncthreads();
    for (int off = 1; off < 512; off <<= 1) {
        int u = (t >= off) ? s[t - off] : 0;
        __syncthreads();
        s[t] += u;
        __syncthreads();
    }
    if (t < ABLK) blockOff[b * ABLK + t] = bs + s[t] - c;
}

// Phase B: partition edges into bucket-ordered packed words (LDS cursors only).
// epk4 = src | (d&255)<<17  (src < 2^17, bucket implied by position)
__global__ __launch_bounds__(256) void part_edges(const int* __restrict__ src,
                                                  const int* __restrict__ dst,
                                                  const int* __restrict__ blockOff,
                                                  int* __restrict__ epk4,
                                                  int E, int epb) {
    __shared__ int lbase[NBKT];
    for (int i = threadIdx.x; i < NBKT; i += 256)
        lbase[i] = blockOff[i * ABLK + blockIdx.x];
    __syncthreads();
    int base = blockIdx.x * epb;
    int end = min(base + epb, E);
    for (int e = base + (int)threadIdx.x; e < end; e += 256) {
        int d = dst[e];
        int p = atomicAdd(&lbase[d >> 8], 1);
        epk4[p] = src[e] | ((d & 255) << 17);
    }
}

// Phase C: per-bucket: node counts -> offsets + dinv + eidx fill (LDS cursors).
// Fused: converts this bucket's emb rows to fp16 scaled by dinv (was f2h_scale).
__global__ __launch_bounds__(256) void build_csr(const int* __restrict__ epk4,
                                                 const int* __restrict__ bktStart,
                                                 int* __restrict__ offsets,
                                                 float* __restrict__ dinv,
                                                 int* __restrict__ eidx,
                                                 const float* __restrict__ emb,
                                                 half_t* __restrict__ zh, int N) {
    __shared__ int ncnt[256];
    __shared__ int noff[256];
    __shared__ int cur[256];
    __shared__ float dvs[256];
    int b = blockIdx.x, t = threadIdx.x;
    int n0 = b << 8;
    int estart = bktStart[b], eend = bktStart[b + 1];
    ncnt[t] = 0;
    __syncthreads();
    for (int e = estart + t; e < eend; e += 256)
        atomicAdd(&ncnt[epk4[e] >> 17], 1);
    __syncthreads();
    int c = ncnt[t];
    noff[t] = c;
    __syncthreads();
    for (int off = 1; off < 256; off <<= 1) {
        int u = (t >= off) ? noff[t - off] : 0;
        __syncthreads();
        noff[t] += u;
        __syncthreads();
    }
    int myoff = estart + noff[t] - c;   // exclusive position of node n0+t
    cur[t] = myoff;
    int node = n0 + t;
    float rs = rsqrtf((float)c + 1.0f);
    dvs[t] = rs;
    if (node < N) {
        offsets[node] = myoff;
        dinv[node] = rs;
        if (node == N - 1) offsets[N] = eend;
    }
    __syncthreads();
    for (int e = estart + t; e < eend; e += 256) {
        int p = epk4[e];
        int pos = atomicAdd(&cur[p >> 17], 1);
        eidx[pos] = p & 0x1FFFF;
    }
    // fp32 -> fp16 convert with dinv scale for this bucket's 256 rows
    const float4* emb4 = (const float4*)emb;
    for (int idx = t; idx < 256 * 32; idx += 256) {
        int row = idx >> 5;
        int nd = n0 + row;
        if (nd < N) {
            float s = dvs[row];
            float4 v = emb4[(size_t)nd * 32 + (idx & 31)];
            half4_t o = {(half_t)(v.x * s), (half_t)(v.y * s),
                         (half_t)(v.z * s), (half_t)(v.w * s)};
            *(half4_t*)(zh + (size_t)nd * DD + (idx & 31) * 4) = o;
        }
    }
}

// ---------------- MFMA fp16 GEMM ----------------
// C[r,c] = epilogue( sum_k A[r,k]*Bt[c,k] )
// BIASRELU: relu(acc + bias[c]);  else: acc * dinv[r]
// BK=128 full-K staging: layer1 (K=128) = ONE stage + one barrier pair + 32 MFMAs;
// layer2 (K=256) = two stages. LDA=136 keeps the free 2-way bank aliasing
// (272 B row stride = 4 banks mod 32, lanes r and r+8 alias -> 2-way, free m136).
// XCD swizzle: the NCB col-blocks sharing one A row-panel land on the SAME XCD.
template <int K, int CT, int NCB, bool BIASRELU>
__global__ __launch_bounds__(256) void gemm_mfma(const half_t* __restrict__ A,
                                                 const half_t* __restrict__ Bt,
                                                 const float* __restrict__ dinv,
                                                 const float* __restrict__ bias,
                                                 half_t* __restrict__ C, int M) {
    constexpr int BK = 128;
    constexpr int LDA = 136;
    __shared__ __align__(16) half_t As[128][LDA];
    __shared__ __align__(16) half_t Bs[64][LDA];

    const int tid = threadIdx.x;
    const int wave = tid >> 6, lane = tid & 63;
    const int wr = wave >> 1, wc = wave & 1;

    // ---- XCD-aware remap: d = bx + NCB*by; rp = (d/(8*NCB))*8 + (d&7); cc = (d>>3)%NCB
    const int d = blockIdx.x + NCB * blockIdx.y;
    const int rp = (d / (8 * NCB)) * 8 + (d & 7);
    const int cc = (d >> 3) % NCB;
    const int row0 = rp * 128;
    const int col0 = cc * 64;
    const int lrow = lane & 15, kq = lane >> 4;

    floatx4 acc[4][2] = {};

    for (int k0 = 0; k0 < K; k0 += BK) {
#pragma unroll
        for (int i = 0; i < 8; ++i) {
            int r = (tid >> 4) + i * 16;
            int kk = (tid & 15) * 8;
            int gr = row0 + r;
            half8 v = {};
            if (gr < M) v = *(const half8*)(A + (size_t)gr * K + k0 + kk);
            *(half8*)&As[r][kk] = v;
        }
#pragma unroll
        for (int i = 0; i < 4; ++i) {
            int n = (tid >> 4) + i * 16;
            int kk = (tid & 15) * 8;
            half8 v = *(const half8*)(Bt + (size_t)(col0 + n) * K + k0 + kk);
            *(half8*)&Bs[n][kk] = v;
        }
        __syncthreads();
#pragma unroll
        for (int ks = 0; ks < 4; ++ks) {
            half8 af[4], bf[2];
#pragma unroll
            for (int i = 0; i < 4; ++i)
                af[i] = *(const half8*)&As[wr * 64 + i * 16 + lrow][ks * 32 + kq * 8];
#pragma unroll
            for (int j = 0; j < 2; ++j)
                bf[j] = *(const half8*)&Bs[wc * 32 + j * 16 + lrow][ks * 32 + kq * 8];
#pragma unroll
            for (int i = 0; i < 4; ++i)
#pragma unroll
                for (int j = 0; j < 2; ++j)
                    acc[i][j] = __builtin_amdgcn_mfma_f32_16x16x32_f16(af[i], bf[j], acc[i][j], 0, 0, 0);
        }
        if (k0 + BK < K) __syncthreads();
    }

    // C/D layout: col = lane&15, row = (lane>>4)*4 + reg
#pragma unroll
    for (int i = 0; i < 4; ++i) {
#pragma unroll
        for (int r = 0; r < 4; ++r) {
            int grow = row0 + wr * 64 + i * 16 + kq * 4 + r;
            if (grow < M) {
                float s = BIASRELU ? 0.f : dinv[grow];
#pragma unroll
                for (int j = 0; j < 2; ++j) {
                    int gcol = col0 + wc * 32 + j * 16 + lrow;
                    float v = acc[i][j][r];
                    if (BIASRELU) v = fmaxf(v + bias[gcol], 0.f);
                    else          v = v * s;
                    C[(size_t)grow * CT + gcol] = (half_t)v;
                }
            }
        }
    }
}

// ---------------- CSR gather-reduce, 128 fp16 channels ----------------
// 8-deep unrolled edge loop: 8 outstanding row-gathers between dependent eidx reads.
template <bool OUT16>
__global__ __launch_bounds__(256) void gather128(const half_t* __restrict__ y,
                                                 void* __restrict__ outv,
                                                 const int* __restrict__ offsets,
                                                 const int* __restrict__ eidx,
                                                 const float* __restrict__ dinv,
                                                 const float* __restrict__ bias, int N) {
    int node = blockIdx.x * 8 + (threadIdx.x >> 5);
    if (node >= N) return;
    int c = (threadIdx.x & 31) * 4;

    half4_t sv = *(const half4_t*)(y + (size_t)node * DD + c);   // self loop
    float a0 = (float)sv[0], a1 = (float)sv[1], a2 = (float)sv[2], a3 = (float)sv[3];
    float b0 = 0.f, b1_ = 0.f, b2_ = 0.f, b3 = 0.f;

    int e = offsets[node];
    const int e1 = offsets[node + 1];
    for (; e + 7 < e1; e += 8) {
        int s0 = eidx[e],     s1 = eidx[e + 1], s2 = eidx[e + 2], s3 = eidx[e + 3];
        int s4 = eidx[e + 4], s5 = eidx[e + 5], s6 = eidx[e + 6], s7 = eidx[e + 7];
        half4_t v0 = *(const half4_t*)(y + (size_t)s0 * DD + c);
        half4_t v1 = *(const half4_t*)(y + (size_t)s1 * DD + c);
        half4_t v2 = *(const half4_t*)(y + (size_t)s2 * DD + c);
        half4_t v3 = *(const half4_t*)(y + (size_t)s3 * DD + c);
        half4_t v4 = *(const half4_t*)(y + (size_t)s4 * DD + c);
        half4_t v5 = *(const half4_t*)(y + (size_t)s5 * DD + c);
        half4_t v6 = *(const half4_t*)(y + (size_t)s6 * DD + c);
        half4_t v7 = *(const half4_t*)(y + (size_t)s7 * DD + c);
        a0 += (float)v0[0]; a1 += (float)v0[1]; a2 += (float)v0[2]; a3 += (float)v0[3];
        b0 += (float)v1[0]; b1_ += (float)v1[1]; b2_ += (float)v1[2]; b3 += (float)v1[3];
        a0 += (float)v2[0]; a1 += (float)v2[1]; a2 += (float)v2[2]; a3 += (float)v2[3];
        b0 += (float)v3[0]; b1_ += (float)v3[1]; b2_ += (float)v3[2]; b3 += (float)v3[3];
        a0 += (float)v4[0]; a1 += (float)v4[1]; a2 += (float)v4[2]; a3 += (float)v4[3];
        b0 += (float)v5[0]; b1_ += (float)v5[1]; b2_ += (float)v5[2]; b3 += (float)v5[3];
        a0 += (float)v6[0]; a1 += (float)v6[1]; a2 += (float)v6[2]; a3 += (float)v6[3];
        b0 += (float)v7[0]; b1_ += (float)v7[1]; b2_ += (float)v7[2]; b3 += (float)v7[3];
    }
    for (; e + 3 < e1; e += 4) {
        int s0 = eidx[e], s1 = eidx[e + 1], s2 = eidx[e + 2], s3 = eidx[e + 3];
        half4_t v0 = *(const half4_t*)(y + (size_t)s0 * DD + c);
        half4_t v1 = *(const half4_t*)(y + (size_t)s1 * DD + c);
        half4_t v2 = *(const half4_t*)(y + (size_t)s2 * DD + c);
        half4_t v3 = *(const half4_t*)(y + (size_t)s3 * DD + c);
        a0 += (float)v0[0]; a1 += (float)v0[1]; a2 += (float)v0[2]; a3 += (float)v0[3];
        b0 += (float)v1[0]; b1_ += (float)v1[1]; b2_ += (float)v1[2]; b3 += (float)v1[3];
        a0 += (float)v2[0]; a1 += (float)v2[1]; a2 += (float)v2[2]; a3 += (float)v2[3];
        b0 += (float)v3[0]; b1_ += (float)v3[1]; b2_ += (float)v3[2]; b3 += (float)v3[3];
    }
    for (; e < e1; ++e) {
        int s0 = eidx[e];
        half4_t v0 = *(const half4_t*)(y + (size_t)s0 * DD + c);
        a0 += (float)v0[0]; a1 += (float)v0[1]; a2 += (float)v0[2]; a3 += (float)v0[3];
    }

    float s = dinv[node];
    float o0 = s * (a0 + b0);
    float o1 = s * (a1 + b1_);
    float o2 = s * (a2 + b2_);
    float o3 = s * (a3 + b3);
    if (OUT16) {
        half4_t o = {(half_t)o0, (half_t)o1, (half_t)o2, (half_t)o3};
        *(half4_t*)((half_t*)outv + (size_t)node * DD + c) = o;
    } else {
        float4 bb = *(const float4*)(bias + c);
        float4 o = make_float4(o0 + bb.x, o1 + bb.y, o2 + bb.z, o3 + bb.w);
        *(float4*)((float*)outv + (size_t)node * DD + c) = o;
    }
}

extern "C" void kernel_launch(void* const* d_in, const int* in_sizes, int n_in,
                              void* d_out, int out_size, void* d_ws, size_t ws_size,
                              hipStream_t stream) {
    const float* emb = (const float*)d_in[0];
    const float* W1  = (const float*)d_in[1];
    const float* b1  = (const float*)d_in[2];
    const float* W2  = (const float*)d_in[3];
    const float* b2  = (const float*)d_in[4];
    const int*   ei  = (const int*)d_in[5];

    const int N = NN;
    const int E = in_sizes[5] / 2;
    const int* src = ei;
    const int* dst = ei + E;

    // workspace layout (bytes)
    char* w = (char*)d_ws;
    float*  dinv = (float*)w;  w += 100032 * 4;
    half_t* zh   = (half_t*)w; w += (size_t)NN * DD * 2;   // emb*dinv; reused as y2
    half_t* g1h  = (half_t*)w; w += (size_t)NN * DD * 2;   // aggregated z
    half_t* x1h  = (half_t*)w; w += (size_t)NN * HH * 2;   // layer-1 output
    half_t* W1t  = (half_t*)w; w += (size_t)DD * HH * 2;
    half_t* W2t  = (half_t*)w; w += (size_t)HH * DD * 2;
    int* offsets = (int*)w;    w += 100032 * 4;
    int* cnt     = (int*)w;    w += (size_t)NBKT * ABLK * 4;
    int* blockOff= (int*)w;    w += (size_t)NBKT * ABLK * 4;
    int* tot     = (int*)w;    w += 512 * 4;
    int* bktStart= (int*)w;    w += 512 * 4;
    int* epk4    = (int*)w;    w += (size_t)E * 4;   // packed src | (d&255)<<17
    int* eidx    = (int*)w;
    float* out   = (float*)d_out;
    half_t* y2h  = zh;         // zh dead after gather1

    const int epb = (E + ABLK - 1) / ABLK;

    // 1. CSR build (all per-edge atomics in LDS); weight transposes ride along
    hipMemsetAsync(tot, 0, NBKT * sizeof(int), stream);
    hist_bkt<<<ABLK + 8, 256, 0, stream>>>(dst, cnt, tot, W1, W2, W1t, W2t, E, epb);
    scan_all<<<NBKT, 512, 0, stream>>>(tot, cnt, bktStart, blockOff);
    part_edges<<<ABLK, 256, 0, stream>>>(src, dst, blockOff, epk4, E, epb);
    build_csr<<<NBKT, 256, 0, stream>>>(epk4, bktStart, offsets, dinv, eidx, emb, zh, N);

    const int gyp = 784;                    // row-panels padded to %8==0 for swizzle
    const int aggBlocks = (N + 7) / 8;

    // 2. layer 1: aggregate-first (g1 = dinv*(z_self + sum z_src)), then GEMM w/ bias+relu
    gather128<true><<<aggBlocks, 256, 0, stream>>>(zh, g1h, offsets, eidx, dinv, nullptr, N);
    gemm_mfma<DD, HH, 4, true><<<dim3(4, gyp), 256, 0, stream>>>(g1h, W1t, dinv, b1, x1h, N);

    // 3. layer 2: GEMM-first (y2 = (x1@W2)*dinv), gather straight into d_out (fp32)
    gemm_mfma<HH, DD, 2, false><<<dim3(2, gyp), 256, 0, stream>>>(x1h, W2t, dinv, nullptr, y2h, N);
    gather128<false><<<aggBlocks, 256, 0, stream>>>(y2h, (void*)out, offsets, eidx, dinv, b2, N);
}

// Round 10
// 371.671 us; speedup vs baseline: 1.0354x; 1.0354x over previous
//
#include <hip/hip_runtime.h>
#include <hip/hip_bf16.h>

#define NN 100000
#define DD 128
#define HH 256

#define NBKT 391   // ceil(NN/256) buckets of 256 nodes (bucket = dst>>8)
#define ABLK 256   // partition blocks for phases A/B (1 per CU)

typedef _Float16 half_t;
typedef _Float16 half8 __attribute__((ext_vector_type(8)));
typedef _Float16 half4_t __attribute__((ext_vector_type(4)));
typedef float floatx4 __attribute__((ext_vector_type(4)));

// ---------------- CSR build, LDS-atomic counting sort ----------------

// Phase A: per-block bucket histogram; cnt[b*ABLK+blk], tot[b] (tot pre-zeroed).
// Blocks >= ABLK do the weight transposes instead (fused launch).
__global__ __launch_bounds__(256) void hist_bkt(const int* __restrict__ dst,
                                                int* __restrict__ cnt,
                                                int* __restrict__ tot,
                                                const float* __restrict__ W1,
                                                const float* __restrict__ W2,
                                                half_t* __restrict__ W1t,
                                                half_t* __restrict__ W2t,
                                                int E, int epb) {
    __shared__ int h[NBKT];
    if (blockIdx.x >= ABLK) {
        // transpose both weights: 8 blocks, grid-stride over 2*DD*HH elements
        for (int i = (blockIdx.x - ABLK) * 256 + (int)threadIdx.x;
             i < 2 * DD * HH; i += 8 * 256) {
            if (i < DD * HH) {                   // W1: K=DD, C=HH
                int k = i / HH, c = i - k * HH;
                W1t[(size_t)c * DD + k] = (half_t)W1[i];
            } else {                             // W2: K=HH, C=DD
                int j = i - DD * HH;
                int k = j / DD, c = j - k * DD;
                W2t[(size_t)c * HH + k] = (half_t)W2[j];
            }
        }
        return;
    }
    for (int i = threadIdx.x; i < NBKT; i += 256) h[i] = 0;
    __syncthreads();
    int base = blockIdx.x * epb;
    int end = min(base + epb, E);
    for (int e = base + (int)threadIdx.x; e < end; e += 256)
        atomicAdd(&h[dst[e] >> 8], 1);
    __syncthreads();
    for (int i = threadIdx.x; i < NBKT; i += 256) {
        int v = h[i];
        cnt[i * ABLK + blockIdx.x] = v;
        if (v) atomicAdd(&tot[i], v);
    }
}

// Fused scan: each block b recomputes the bucket prefix (391 ints, trivial) and
// scans its own cnt[b][0..ABLK-1] -> bktStart[b] + blockOff[b][*].
__global__ __launch_bounds__(512) void scan_all(const int* __restrict__ tot,
                                                const int* __restrict__ cnt,
                                                int* __restrict__ bktStart,
                                                int* __restrict__ blockOff) {
    __shared__ int s[512];
    int b = blockIdx.x, t = threadIdx.x;
    int v = (t < NBKT) ? tot[t] : 0;
    s[t] = v;
    __syncthreads();
    for (int off = 1; off < 512; off <<= 1) {
        int u = (t >= off) ? s[t - off] : 0;
        __syncthreads();
        s[t] += u;
        __syncthreads();
    }
    int bs = (b > 0) ? s[b - 1] : 0;       // exclusive start of bucket b
    int tail = s[NBKT - 1];                // == E
    __syncthreads();
    if (t == 0) {
        bktStart[b] = bs;
        if (b == NBKT - 1) bktStart[NBKT] = tail;
    }
    int c = (t < ABLK) ? cnt[b * ABLK + t] : 0;
    s[t] = c;
    __syncthreads();
    for (int off = 1; off < 512; off <<= 1) {
        int u = (t >= off) ? s[t - off] : 0;
        __syncthreads();
        s[t] += u;
        __syncthreads();
    }
    if (t < ABLK) blockOff[b * ABLK + t] = bs + s[t] - c;
}

// Phase B: partition edges into bucket-ordered packed words (LDS cursors only).
// epk4 = src | (d&255)<<17  (src < 2^17, bucket implied by position)
__global__ __launch_bounds__(256) void part_edges(const int* __restrict__ src,
                                                  const int* __restrict__ dst,
                                                  const int* __restrict__ blockOff,
                                                  int* __restrict__ epk4,
                                                  int E, int epb) {
    __shared__ int lbase[NBKT];
    for (int i = threadIdx.x; i < NBKT; i += 256)
        lbase[i] = blockOff[i * ABLK + blockIdx.x];
    __syncthreads();
    int base = blockIdx.x * epb;
    int end = min(base + epb, E);
    for (int e = base + (int)threadIdx.x; e < end; e += 256) {
        int d = dst[e];
        int p = atomicAdd(&lbase[d >> 8], 1);
        epk4[p] = src[e] | ((d & 255) << 17);
    }
}

// Phase C: per-bucket: node counts -> offsets + dinv + eidx fill (LDS cursors).
// Fused: converts this bucket's emb rows to fp16 scaled by dinv (was f2h_scale).
__global__ __launch_bounds__(256) void build_csr(const int* __restrict__ epk4,
                                                 const int* __restrict__ bktStart,
                                                 int* __restrict__ offsets,
                                                 float* __restrict__ dinv,
                                                 int* __restrict__ eidx,
                                                 const float* __restrict__ emb,
                                                 half_t* __restrict__ zh, int N) {
    __shared__ int ncnt[256];
    __shared__ int noff[256];
    __shared__ int cur[256];
    __shared__ float dvs[256];
    int b = blockIdx.x, t = threadIdx.x;
    int n0 = b << 8;
    int estart = bktStart[b], eend = bktStart[b + 1];
    ncnt[t] = 0;
    __syncthreads();
    for (int e = estart + t; e < eend; e += 256)
        atomicAdd(&ncnt[epk4[e] >> 17], 1);
    __syncthreads();
    int c = ncnt[t];
    noff[t] = c;
    __syncthreads();
    for (int off = 1; off < 256; off <<= 1) {
        int u = (t >= off) ? noff[t - off] : 0;
        __syncthreads();
        noff[t] += u;
        __syncthreads();
    }
    int myoff = estart + noff[t] - c;   // exclusive position of node n0+t
    cur[t] = myoff;
    int node = n0 + t;
    float rs = rsqrtf((float)c + 1.0f);
    dvs[t] = rs;
    if (node < N) {
        offsets[node] = myoff;
        dinv[node] = rs;
        if (node == N - 1) offsets[N] = eend;
    }
    __syncthreads();
    for (int e = estart + t; e < eend; e += 256) {
        int p = epk4[e];
        int pos = atomicAdd(&cur[p >> 17], 1);
        eidx[pos] = p & 0x1FFFF;
    }
    // fp32 -> fp16 convert with dinv scale for this bucket's 256 rows
    const float4* emb4 = (const float4*)emb;
    for (int idx = t; idx < 256 * 32; idx += 256) {
        int row = idx >> 5;
        int nd = n0 + row;
        if (nd < N) {
            float s = dvs[row];
            float4 v = emb4[(size_t)nd * 32 + (idx & 31)];
            half4_t o = {(half_t)(v.x * s), (half_t)(v.y * s),
                         (half_t)(v.z * s), (half_t)(v.w * s)};
            *(half4_t*)(zh + (size_t)nd * DD + (idx & 31) * 4) = o;
        }
    }
}

// ---------------- MFMA fp16 GEMM ----------------
// C[r,c] = epilogue( sum_k A[r,k]*Bt[c,k] )
// BIASRELU: relu(acc + bias[c]);  else: acc * dinv[r]
// BK=64 / LDA=72 (round-8 measured-good config; BK=128 regressed per m132:
// 52 KB LDS cut occupancy 5->3 blocks/CU and lost more TLP than barriers saved).
// XCD swizzle: the NCB col-blocks sharing one A row-panel land on the SAME XCD.
template <int K, int CT, int NCB, bool BIASRELU>
__global__ __launch_bounds__(256) void gemm_mfma(const half_t* __restrict__ A,
                                                 const half_t* __restrict__ Bt,
                                                 const float* __restrict__ dinv,
                                                 const float* __restrict__ bias,
                                                 half_t* __restrict__ C, int M) {
    constexpr int BK = 64;
    constexpr int LDA = 72;   // halves; 144 B stride -> free 2-way bank aliasing
    __shared__ __align__(16) half_t As[128][LDA];
    __shared__ __align__(16) half_t Bs[64][LDA];

    const int tid = threadIdx.x;
    const int wave = tid >> 6, lane = tid & 63;
    const int wr = wave >> 1, wc = wave & 1;

    // ---- XCD-aware remap: d = bx + NCB*by; rp = (d/(8*NCB))*8 + (d&7); cc = (d>>3)%NCB
    const int d = blockIdx.x + NCB * blockIdx.y;
    const int rp = (d / (8 * NCB)) * 8 + (d & 7);
    const int cc = (d >> 3) % NCB;
    const int row0 = rp * 128;
    const int col0 = cc * 64;
    const int lrow = lane & 15, kq = lane >> 4;

    floatx4 acc[4][2] = {};

    for (int k0 = 0; k0 < K; k0 += BK) {
#pragma unroll
        for (int i = 0; i < 4; ++i) {
            int r = (tid >> 3) + i * 32;
            int kk = (tid & 7) * 8;
            int gr = row0 + r;
            half8 v = {};
            if (gr < M) v = *(const half8*)(A + (size_t)gr * K + k0 + kk);
            *(half8*)&As[r][kk] = v;
        }
#pragma unroll
        for (int i = 0; i < 2; ++i) {
            int n = (tid >> 3) + i * 32;
            int kk = (tid & 7) * 8;
            half8 v = *(const half8*)(Bt + (size_t)(col0 + n) * K + k0 + kk);
            *(half8*)&Bs[n][kk] = v;
        }
        __syncthreads();
#pragma unroll
        for (int ks = 0; ks < 2; ++ks) {
            half8 af[4], bf[2];
#pragma unroll
            for (int i = 0; i < 4; ++i)
                af[i] = *(const half8*)&As[wr * 64 + i * 16 + lrow][ks * 32 + kq * 8];
#pragma unroll
            for (int j = 0; j < 2; ++j)
                bf[j] = *(const half8*)&Bs[wc * 32 + j * 16 + lrow][ks * 32 + kq * 8];
#pragma unroll
            for (int i = 0; i < 4; ++i)
#pragma unroll
                for (int j = 0; j < 2; ++j)
                    acc[i][j] = __builtin_amdgcn_mfma_f32_16x16x32_f16(af[i], bf[j], acc[i][j], 0, 0, 0);
        }
        __syncthreads();
    }

    // C/D layout: col = lane&15, row = (lane>>4)*4 + reg
#pragma unroll
    for (int i = 0; i < 4; ++i) {
#pragma unroll
        for (int r = 0; r < 4; ++r) {
            int grow = row0 + wr * 64 + i * 16 + kq * 4 + r;
            if (grow < M) {
                float s = BIASRELU ? 0.f : dinv[grow];
#pragma unroll
                for (int j = 0; j < 2; ++j) {
                    int gcol = col0 + wc * 32 + j * 16 + lrow;
                    float v = acc[i][j][r];
                    if (BIASRELU) v = fmaxf(v + bias[gcol], 0.f);
                    else          v = v * s;
                    C[(size_t)grow * CT + gcol] = (half_t)v;
                }
            }
        }
    }
}

// ---------------- CSR gather-reduce, 128 fp16 channels ----------------
// 8-deep unrolled edge loop: 8 outstanding row-gathers between dependent eidx reads.
template <bool OUT16>
__global__ __launch_bounds__(256) void gather128(const half_t* __restrict__ y,
                                                 void* __restrict__ outv,
                                                 const int* __restrict__ offsets,
                                                 const int* __restrict__ eidx,
                                                 const float* __restrict__ dinv,
                                                 const float* __restrict__ bias, int N) {
    int node = blockIdx.x * 8 + (threadIdx.x >> 5);
    if (node >= N) return;
    int c = (threadIdx.x & 31) * 4;

    half4_t sv = *(const half4_t*)(y + (size_t)node * DD + c);   // self loop
    float a0 = (float)sv[0], a1 = (float)sv[1], a2 = (float)sv[2], a3 = (float)sv[3];
    float b0 = 0.f, b1_ = 0.f, b2_ = 0.f, b3 = 0.f;

    int e = offsets[node];
    const int e1 = offsets[node + 1];
    for (; e + 7 < e1; e += 8) {
        int s0 = eidx[e],     s1 = eidx[e + 1], s2 = eidx[e + 2], s3 = eidx[e + 3];
        int s4 = eidx[e + 4], s5 = eidx[e + 5], s6 = eidx[e + 6], s7 = eidx[e + 7];
        half4_t v0 = *(const half4_t*)(y + (size_t)s0 * DD + c);
        half4_t v1 = *(const half4_t*)(y + (size_t)s1 * DD + c);
        half4_t v2 = *(const half4_t*)(y + (size_t)s2 * DD + c);
        half4_t v3 = *(const half4_t*)(y + (size_t)s3 * DD + c);
        half4_t v4 = *(const half4_t*)(y + (size_t)s4 * DD + c);
        half4_t v5 = *(const half4_t*)(y + (size_t)s5 * DD + c);
        half4_t v6 = *(const half4_t*)(y + (size_t)s6 * DD + c);
        half4_t v7 = *(const half4_t*)(y + (size_t)s7 * DD + c);
        a0 += (float)v0[0]; a1 += (float)v0[1]; a2 += (float)v0[2]; a3 += (float)v0[3];
        b0 += (float)v1[0]; b1_ += (float)v1[1]; b2_ += (float)v1[2]; b3 += (float)v1[3];
        a0 += (float)v2[0]; a1 += (float)v2[1]; a2 += (float)v2[2]; a3 += (float)v2[3];
        b0 += (float)v3[0]; b1_ += (float)v3[1]; b2_ += (float)v3[2]; b3 += (float)v3[3];
        a0 += (float)v4[0]; a1 += (float)v4[1]; a2 += (float)v4[2]; a3 += (float)v4[3];
        b0 += (float)v5[0]; b1_ += (float)v5[1]; b2_ += (float)v5[2]; b3 += (float)v5[3];
        a0 += (float)v6[0]; a1 += (float)v6[1]; a2 += (float)v6[2]; a3 += (float)v6[3];
        b0 += (float)v7[0]; b1_ += (float)v7[1]; b2_ += (float)v7[2]; b3 += (float)v7[3];
    }
    for (; e + 3 < e1; e += 4) {
        int s0 = eidx[e], s1 = eidx[e + 1], s2 = eidx[e + 2], s3 = eidx[e + 3];
        half4_t v0 = *(const half4_t*)(y + (size_t)s0 * DD + c);
        half4_t v1 = *(const half4_t*)(y + (size_t)s1 * DD + c);
        half4_t v2 = *(const half4_t*)(y + (size_t)s2 * DD + c);
        half4_t v3 = *(const half4_t*)(y + (size_t)s3 * DD + c);
        a0 += (float)v0[0]; a1 += (float)v0[1]; a2 += (float)v0[2]; a3 += (float)v0[3];
        b0 += (float)v1[0]; b1_ += (float)v1[1]; b2_ += (float)v1[2]; b3 += (float)v1[3];
        a0 += (float)v2[0]; a1 += (float)v2[1]; a2 += (float)v2[2]; a3 += (float)v2[3];
        b0 += (float)v3[0]; b1_ += (float)v3[1]; b2_ += (float)v3[2]; b3 += (float)v3[3];
    }
    for (; e < e1; ++e) {
        int s0 = eidx[e];
        half4_t v0 = *(const half4_t*)(y + (size_t)s0 * DD + c);
        a0 += (float)v0[0]; a1 += (float)v0[1]; a2 += (float)v0[2]; a3 += (float)v0[3];
    }

    float s = dinv[node];
    float o0 = s * (a0 + b0);
    float o1 = s * (a1 + b1_);
    float o2 = s * (a2 + b2_);
    float o3 = s * (a3 + b3);
    if (OUT16) {
        half4_t o = {(half_t)o0, (half_t)o1, (half_t)o2, (half_t)o3};
        *(half4_t*)((half_t*)outv + (size_t)node * DD + c) = o;
    } else {
        float4 bb = *(const float4*)(bias + c);
        float4 o = make_float4(o0 + bb.x, o1 + bb.y, o2 + bb.z, o3 + bb.w);
        *(float4*)((float*)outv + (size_t)node * DD + c) = o;
    }
}

extern "C" void kernel_launch(void* const* d_in, const int* in_sizes, int n_in,
                              void* d_out, int out_size, void* d_ws, size_t ws_size,
                              hipStream_t stream) {
    const float* emb = (const float*)d_in[0];
    const float* W1  = (const float*)d_in[1];
    const float* b1  = (const float*)d_in[2];
    const float* W2  = (const float*)d_in[3];
    const float* b2  = (const float*)d_in[4];
    const int*   ei  = (const int*)d_in[5];

    const int N = NN;
    const int E = in_sizes[5] / 2;
    const int* src = ei;
    const int* dst = ei + E;

    // workspace layout (bytes)
    char* w = (char*)d_ws;
    float*  dinv = (float*)w;  w += 100032 * 4;
    half_t* zh   = (half_t*)w; w += (size_t)NN * DD * 2;   // emb*dinv; reused as y2
    half_t* g1h  = (half_t*)w; w += (size_t)NN * DD * 2;   // aggregated z
    half_t* x1h  = (half_t*)w; w += (size_t)NN * HH * 2;   // layer-1 output
    half_t* W1t  = (half_t*)w; w += (size_t)DD * HH * 2;
    half_t* W2t  = (half_t*)w; w += (size_t)HH * DD * 2;
    int* offsets = (int*)w;    w += 100032 * 4;
    int* cnt     = (int*)w;    w += (size_t)NBKT * ABLK * 4;
    int* blockOff= (int*)w;    w += (size_t)NBKT * ABLK * 4;
    int* tot     = (int*)w;    w += 512 * 4;
    int* bktStart= (int*)w;    w += 512 * 4;
    int* epk4    = (int*)w;    w += (size_t)E * 4;   // packed src | (d&255)<<17
    int* eidx    = (int*)w;
    float* out   = (float*)d_out;
    half_t* y2h  = zh;         // zh dead after gather1

    const int epb = (E + ABLK - 1) / ABLK;

    // 1. CSR build (all per-edge atomics in LDS); weight transposes ride along
    hipMemsetAsync(tot, 0, NBKT * sizeof(int), stream);
    hist_bkt<<<ABLK + 8, 256, 0, stream>>>(dst, cnt, tot, W1, W2, W1t, W2t, E, epb);
    scan_all<<<NBKT, 512, 0, stream>>>(tot, cnt, bktStart, blockOff);
    part_edges<<<ABLK, 256, 0, stream>>>(src, dst, blockOff, epk4, E, epb);
    build_csr<<<NBKT, 256, 0, stream>>>(epk4, bktStart, offsets, dinv, eidx, emb, zh, N);

    const int gyp = 784;                    // row-panels padded to %8==0 for swizzle
    const int aggBlocks = (N + 7) / 8;

    // 2. layer 1: aggregate-first (g1 = dinv*(z_self + sum z_src)), then GEMM w/ bias+relu
    gather128<true><<<aggBlocks, 256, 0, stream>>>(zh, g1h, offsets, eidx, dinv, nullptr, N);
    gemm_mfma<DD, HH, 4, true><<<dim3(4, gyp), 256, 0, stream>>>(g1h, W1t, dinv, b1, x1h, N);

    // 3. layer 2: GEMM-first (y2 = (x1@W2)*dinv), gather straight into d_out (fp32)
    gemm_mfma<HH, DD, 2, false><<<dim3(2, gyp), 256, 0, stream>>>(x1h, W2t, dinv, nullptr, y2h, N);
    gather128<false><<<aggBlocks, 256, 0, stream>>>(y2h, (void*)out, offsets, eidx, dinv, b2, N);
}